// Round 1
// baseline (1372.715 us; speedup 1.0000x reference)
//
#include <hip/hip_runtime.h>

#define HN 4096
#define HROWS 8192

// Producer blocks for inline permutation extraction. Deadlock-safety:
// __launch_bounds__(256,4) caps VGPR<=128 and LDS=39.4KB*4=157.6KB<=160KB,
// guaranteeing 4 blocks/CU * 256 CU = 1024 co-resident blocks >= NPROD=512.
// Tickets are taken in *execution* order (atomicAdd at block start), so the
// 512 producers are by construction the first 512 running blocks; they reach
// the done-increment with no prior waits.
#define NPROD 512u
#define CHUNK ((HN * HN / 4) / (int)NPROD)  // float4s per producer block = 8192

// ---------------------------------------------------------------------------
// 16-point unnormalized Walsh-Hadamard transform in registers (64 add/sub).
// ---------------------------------------------------------------------------
__device__ __forceinline__ void fwht16(float* x) {
#pragma unroll
    for (int s = 1; s < 16; s <<= 1) {
#pragma unroll
        for (int i = 0; i < 16; ++i) {
            if ((i & s) == 0) {
                float u = x[i], w = x[i + s];
                x[i] = u + w;
                x[i + s] = u - w;
            }
        }
    }
}

// Padded LDS slot for the FWHT work buffer: breaks power-of-2 strides.
// slot(j) = j + 4*(j>>4) + 8*(j>>8); max slot(4095) = 5235.
#define WORK_SZ 5248
// Padded slot for the original-row buffer (gather source): i + 4*(i>>5).
#define ORIG_SZ 4608

// ---------------------------------------------------------------------------
// Fused kernel: one block per row.
//   prologue (first NPROD scheduled blocks only): extract inv[] slice from the
//     one-hot P. P[i, perm[i]] = 1 => inv[perm[i]] = i, (v@P)[r,j] = v[r,inv[j]].
//   main: out[r,:] = FWHT(v[r,:])/64 + v[r, inv[:]]
//     Round 1: bits 0-3 (contiguous, from global regs)
//     Round 2: bits 4-7 (LDS stride-20 after padding -> 2-way, free)
//     Round 3: bits 8-11 (LDS stride-328 -> <=3-way)
//   the inv-ready wait sits AFTER round 3, so extraction (64 MB read) overlaps
//   the FWHT row streaming instead of serializing in front of it.
// ---------------------------------------------------------------------------
__global__ __launch_bounds__(256, 4)
void fused_fwht_perm(const float* __restrict__ val,
                     const float4* __restrict__ P4,
                     float* __restrict__ out,
                     unsigned* __restrict__ ws) {
    __shared__ __align__(16) float work[WORK_SZ];
    __shared__ __align__(16) float orig[ORIG_SZ];
    __shared__ unsigned ticket_s;

    unsigned* ctr = ws;            // ctr[0] = ticket counter, ctr[1] = done count
    int* inv = (int*)(ws + 64);    // 4096 ints at byte offset 256

    const int t = threadIdx.x;
    if (t == 0) ticket_s = atomicAdd(&ctr[0], 1u);

    const int row = blockIdx.x;
    const float* vr = val + (size_t)row * HN;
    float* outr = out + (size_t)row * HN;

    // Issue the row loads before the (possible) extraction detour so they are
    // in flight during it.
    const float4* vr4 = (const float4*)vr + (t << 2);
    float4 a0 = vr4[0], a1 = vr4[1], a2 = vr4[2], a3 = vr4[3];

    __syncthreads();
    const unsigned ticket = ticket_s;

    if (ticket < NPROD) {
        // ---- producer: extract a 128 KB slice of P into inv ----
        int i = (int)ticket * CHUNK + t;
#pragma unroll 8
        for (int it = 0; it < CHUNK / 256; ++it, i += 256) {
            float4 p = P4[i];
            if (p.x != 0.0f || p.y != 0.0f || p.z != 0.0f || p.w != 0.0f) {
                int base = i << 2;
                int prow = base >> 12;        // / 4096
                int pcol = base & (HN - 1);   // % 4096
                if (p.x != 0.0f) inv[pcol]     = prow;
                if (p.y != 0.0f) inv[pcol + 1] = prow;
                if (p.z != 0.0f) inv[pcol + 2] = prow;
                if (p.w != 0.0f) inv[pcol + 3] = prow;
            }
        }
        __threadfence();                       // release: flush inv stores device-wide
        __syncthreads();                       // all threads of this block fenced
        if (t == 0)
            __hip_atomic_fetch_add(&ctr[1], 1u, __ATOMIC_RELEASE,
                                   __HIP_MEMORY_SCOPE_AGENT);
    }

    float x[16];

    // ---- Round 1: thread t owns j = 16t + c, c = 0..15 ----
    // Save original row for the permutation gather (padded, b128 writes,
    // balanced banks: bases cycle through 8 distinct values covering all 32).
    float4* o4 = (float4*)(orig + (t << 4) + ((t >> 1) << 2));
    o4[0] = a0; o4[1] = a1; o4[2] = a2; o4[3] = a3;

    x[0] = a0.x; x[1] = a0.y; x[2]  = a0.z; x[3]  = a0.w;
    x[4] = a1.x; x[5] = a1.y; x[6]  = a1.z; x[7]  = a1.w;
    x[8] = a2.x; x[9] = a2.y; x[10] = a2.z; x[11] = a2.w;
    x[12] = a3.x; x[13] = a3.y; x[14] = a3.z; x[15] = a3.w;

    fwht16(x);

    // slot(16t + c) = 20t + 8*(t>>4) + c : contiguous, 16B-aligned base.
    float4* w4 = (float4*)(work + 20 * t + ((t >> 4) << 3));
    w4[0] = make_float4(x[0],  x[1],  x[2],  x[3]);
    w4[1] = make_float4(x[4],  x[5],  x[6],  x[7]);
    w4[2] = make_float4(x[8],  x[9],  x[10], x[11]);
    w4[3] = make_float4(x[12], x[13], x[14], x[15]);
    __syncthreads();

    const int hi = t >> 4;
    const int lo = t & 15;

    // ---- Round 2: thread (a=hi, c=lo) owns j = 256a + 16m + c over m ----
    // slot = 328a + 20m + c
    {
        const int base = 328 * hi + lo;
#pragma unroll
        for (int m = 0; m < 16; ++m) x[m] = work[base + 20 * m];
        fwht16(x);
#pragma unroll
        for (int m = 0; m < 16; ++m) work[base + 20 * m] = x[m];
    }
    __syncthreads();

    // ---- Round 3: thread (b=hi, c=lo) owns j = 256m + 16b + c over m ----
    // slot = 328m + 20b + c
    {
        const int base = 20 * hi + lo;
#pragma unroll
        for (int m = 0; m < 16; ++m) x[m] = work[base + 328 * m];
        fwht16(x);
    }

    // ---- Wait for inv to be published (overlapped with all work above) ----
    // Unsigned compare: a poisoned, never-reset counter (repeated nonzero byte
    // pattern) reads as >= NPROD, so a bare rocprof kernel replay degrades to
    // stale inv values instead of an infinite spin.
    if (t == 0) {
        while (__hip_atomic_load(ctr + 1, __ATOMIC_RELAXED,
                                 __HIP_MEMORY_SCOPE_AGENT) < NPROD)
            __builtin_amdgcn_s_sleep(16);
    }
    __syncthreads();
    __threadfence();   // acquire: invalidate caches so inv reads are fresh

    // ---- Epilogue: out[j] = fwht[j]/64 + orig[inv[j]] ----
    // j = 256m + t : per-instruction wave stores are 256B contiguous.
    const int j0 = (hi << 4) | lo;  // == t
#pragma unroll
    for (int m = 0; m < 16; ++m) {
        int j = (m << 8) + j0;
        int src = inv[j];                       // coalesced 256B int loads (L1/L2 hit)
        int so = src + ((src >> 5) << 2);       // padded orig slot
        outr[j] = x[m] * 0.015625f + orig[so];  // 1/64 = 1/sqrt(4096)
    }
}

extern "C" void kernel_launch(void* const* d_in, const int* in_sizes, int n_in,
                              void* d_out, int out_size, void* d_ws, size_t ws_size,
                              hipStream_t stream) {
    const float* value = (const float*)d_in[0];
    // d_in[1] (weight) is the Sylvester Hadamard matrix / sqrt(N) by
    // construction -- computed analytically via FWHT, never read.
    const float* permutation = (const float*)d_in[2];
    float* out = (float*)d_out;
    unsigned* ws = (unsigned*)d_ws;

    // Zero the ticket/done counters (graph-capturable async memset).
    hipMemsetAsync(d_ws, 0, 16, stream);
    fused_fwht_perm<<<HROWS, 256, 0, stream>>>(
        value, (const float4*)permutation, out, ws);
}

// Round 2
// 601.609 us; speedup vs baseline: 2.2817x; 2.2817x over previous
//
#include <hip/hip_runtime.h>

#define HN 4096
#define HROWS 8192

// Producer blocks for inline permutation extraction. Deadlock-safety:
// __launch_bounds__(256,4) + LDS 39936B => 4 blocks/CU * 256 CU = 1024
// co-resident blocks >= NPROD=512. Tickets are taken in *execution* order
// (atomicAdd at block start), so the 512 producers are by construction among
// the first 1024 running blocks and reach publication with no prior waits.
#define NPROD 512u
#define CHUNK ((HN * HN / 4) / (int)NPROD)  // float4s per producer block = 8192

// ---------------------------------------------------------------------------
// 16-point unnormalized Walsh-Hadamard transform in registers (64 add/sub).
// ---------------------------------------------------------------------------
__device__ __forceinline__ void fwht16(float* x) {
#pragma unroll
    for (int s = 1; s < 16; s <<= 1) {
#pragma unroll
        for (int i = 0; i < 16; ++i) {
            if ((i & s) == 0) {
                float u = x[i], w = x[i + s];
                x[i] = u + w;
                x[i + s] = u - w;
            }
        }
    }
}

// Padded LDS slot for the FWHT work buffer: breaks power-of-2 strides.
// slot(j) = j + 4*(j>>4) + 8*(j>>8); max slot(4095) = 5235.
#define WORK_SZ 5248
// Padded slot for the original-row buffer (gather source): i + 4*(i>>5).
#define ORIG_SZ 4608

// ---------------------------------------------------------------------------
// Fused kernel: one block per row.
//   prologue (first NPROD ticketed blocks): extract inv[] slice from one-hot P.
//   P[i, perm[i]] = 1 => inv[perm[i]] = i, (v@P)[r,j] = v[r,inv[j]].
//   main: out[r,:] = FWHT(v[r,:])/64 + v[r, inv[:]]
//   The inv-ready wait sits AFTER round 3, so the 64 MB extraction read
//   overlaps the FWHT row streaming instead of serializing in front of it.
//
// SYNC DESIGN (round-1 lesson): NO __threadfence / acquire / release anywhere.
// On multi-XCD gfx950 those lower to whole-cache buffer_inv / buffer_wbl2
// maintenance ops (~1 ms for 8K blocks, measured round 1). All cross-block
// data goes through per-instruction agent-scope RELAXED atomics (sc0/sc1
// flagged loads/stores at the coherence point — no cache maintenance).
// Producer publication: write-through inv stores + s_waitcnt vmcnt(0) +
// __syncthreads + relaxed RMW — the standard release sequence minus the wbl2
// that is only required for *write-back cached* prior stores (ours bypass).
// ---------------------------------------------------------------------------
__global__ __launch_bounds__(256, 4)
void fused_fwht_perm(const float* __restrict__ val,
                     const float4* __restrict__ P4,
                     float* __restrict__ out,
                     unsigned* __restrict__ ws) {
    __shared__ __align__(16) float work[WORK_SZ];
    __shared__ __align__(16) float orig[ORIG_SZ];
    __shared__ unsigned ticket_s;

    unsigned* ctr = ws;            // ctr[0] = ticket counter, ctr[1] = done count
    int* inv = (int*)(ws + 64);    // 4096 ints at byte offset 256

    const int t = threadIdx.x;
    if (t == 0) ticket_s = atomicAdd(&ctr[0], 1u);   // device-scope, no fence

    const int row = blockIdx.x;
    const float* vr = val + (size_t)row * HN;
    float* outr = out + (size_t)row * HN;

    // Issue the row loads before the (possible) extraction detour so they are
    // in flight during it.
    const float4* vr4 = (const float4*)vr + (t << 2);
    float4 a0 = vr4[0], a1 = vr4[1], a2 = vr4[2], a3 = vr4[3];

    __syncthreads();
    const unsigned ticket = ticket_s;

    if (ticket < NPROD) {
        // ---- producer: extract a 128 KB slice of P into inv ----
        int i = (int)ticket * CHUNK + t;
#pragma unroll 8
        for (int it = 0; it < CHUNK / 256; ++it, i += 256) {
            float4 p = P4[i];
            if (p.x != 0.0f || p.y != 0.0f || p.z != 0.0f || p.w != 0.0f) {
                int base = i << 2;
                int prow = base >> 12;        // / 4096
                int pcol = base & (HN - 1);   // % 4096
                // Write-through to the coherence point; no cache maintenance.
                if (p.x != 0.0f) __hip_atomic_store(&inv[pcol],     prow,
                        __ATOMIC_RELAXED, __HIP_MEMORY_SCOPE_AGENT);
                if (p.y != 0.0f) __hip_atomic_store(&inv[pcol + 1], prow,
                        __ATOMIC_RELAXED, __HIP_MEMORY_SCOPE_AGENT);
                if (p.z != 0.0f) __hip_atomic_store(&inv[pcol + 2], prow,
                        __ATOMIC_RELAXED, __HIP_MEMORY_SCOPE_AGENT);
                if (p.w != 0.0f) __hip_atomic_store(&inv[pcol + 3], prow,
                        __ATOMIC_RELAXED, __HIP_MEMORY_SCOPE_AGENT);
            }
        }
        // Drain this thread's write-through stores to the coherence point.
        asm volatile("s_waitcnt vmcnt(0)" ::: "memory");
        __syncthreads();   // all threads of this block drained
        if (t == 0)
            __hip_atomic_fetch_add(&ctr[1], 1u, __ATOMIC_RELAXED,
                                   __HIP_MEMORY_SCOPE_AGENT);
    }

    float x[16];

    // ---- Round 1: thread t owns j = 16t + c, c = 0..15 ----
    // Save original row for the permutation gather (padded, b128 writes,
    // balanced banks: bases cycle through 8 distinct values covering all 32).
    float4* o4 = (float4*)(orig + (t << 4) + ((t >> 1) << 2));
    o4[0] = a0; o4[1] = a1; o4[2] = a2; o4[3] = a3;

    x[0] = a0.x; x[1] = a0.y; x[2]  = a0.z; x[3]  = a0.w;
    x[4] = a1.x; x[5] = a1.y; x[6]  = a1.z; x[7]  = a1.w;
    x[8] = a2.x; x[9] = a2.y; x[10] = a2.z; x[11] = a2.w;
    x[12] = a3.x; x[13] = a3.y; x[14] = a3.z; x[15] = a3.w;

    fwht16(x);

    // slot(16t + c) = 20t + 8*(t>>4) + c : contiguous, 16B-aligned base.
    float4* w4 = (float4*)(work + 20 * t + ((t >> 4) << 3));
    w4[0] = make_float4(x[0],  x[1],  x[2],  x[3]);
    w4[1] = make_float4(x[4],  x[5],  x[6],  x[7]);
    w4[2] = make_float4(x[8],  x[9],  x[10], x[11]);
    w4[3] = make_float4(x[12], x[13], x[14], x[15]);
    __syncthreads();

    const int hi = t >> 4;
    const int lo = t & 15;

    // ---- Round 2: thread (a=hi, c=lo) owns j = 256a + 16m + c over m ----
    // slot = 328a + 20m + c
    {
        const int base = 328 * hi + lo;
#pragma unroll
        for (int m = 0; m < 16; ++m) x[m] = work[base + 20 * m];
        fwht16(x);
#pragma unroll
        for (int m = 0; m < 16; ++m) work[base + 20 * m] = x[m];
    }
    __syncthreads();

    // ---- Round 3: thread (b=hi, c=lo) owns j = 256m + 16b + c over m ----
    // slot = 328m + 20b + c
    {
        const int base = 20 * hi + lo;
#pragma unroll
        for (int m = 0; m < 16; ++m) x[m] = work[base + 328 * m];
        fwht16(x);
    }

    // ---- Wait for inv publication (overlapped with all the work above) ----
    // Relaxed agent load: goes to the coherence point, no buffer_inv.
    // Unsigned compare: a poisoned, never-reset counter reads >= NPROD, so a
    // bare rocprof kernel replay degrades to stale inv, never a hang.
    if (t == 0) {
        while (__hip_atomic_load(&ctr[1], __ATOMIC_RELAXED,
                                 __HIP_MEMORY_SCOPE_AGENT) < NPROD)
            __builtin_amdgcn_s_sleep(8);
    }
    __syncthreads();   // block-level barrier: orders inv loads after the spin

    // ---- Epilogue: out[j] = fwht[j]/64 + orig[inv[j]] ----
    // j = 256m + t : per-instruction wave stores are 256B contiguous.
    // inv loads: relaxed agent-scope (coherence-point reads, coalesced 256B,
    // Infinity-Cache resident -> no HBM traffic, latency hidden by 16 waves/CU).
    const int j0 = (hi << 4) | lo;  // == t
#pragma unroll
    for (int m = 0; m < 16; ++m) {
        int j = (m << 8) + j0;
        int src = __hip_atomic_load(&inv[j], __ATOMIC_RELAXED,
                                    __HIP_MEMORY_SCOPE_AGENT);
        int so = src + ((src >> 5) << 2);       // padded orig slot
        outr[j] = x[m] * 0.015625f + orig[so];  // 1/64 = 1/sqrt(4096)
    }
}

extern "C" void kernel_launch(void* const* d_in, const int* in_sizes, int n_in,
                              void* d_out, int out_size, void* d_ws, size_t ws_size,
                              hipStream_t stream) {
    const float* value = (const float*)d_in[0];
    // d_in[1] (weight) is the Sylvester Hadamard matrix / sqrt(N) by
    // construction -- computed analytically via FWHT, never read.
    const float* permutation = (const float*)d_in[2];
    float* out = (float*)d_out;
    unsigned* ws = (unsigned*)d_ws;

    // Zero the ticket/done counters (graph-capturable async memset).
    hipMemsetAsync(d_ws, 0, 16, stream);
    fused_fwht_perm<<<HROWS, 256, 0, stream>>>(
        value, (const float4*)permutation, out, ws);
}

// Round 3
// 295.332 us; speedup vs baseline: 4.6480x; 2.0371x over previous
//
#include <hip/hip_runtime.h>

#define HN 4096
#define HROWS 8192

// ---------------------------------------------------------------------------
// Kernel A: extract inverse permutation from one-hot matrix P.
// P[i, perm[i]] = 1  =>  inv[perm[i]] = i, so (v @ P)[r, j] = v[r, inv[j]].
// Pure 64 MB streaming read (L3-resident in steady state); writes 16 KB.
// ---------------------------------------------------------------------------
__global__ void extract_inv_kernel(const float4* __restrict__ P4,
                                   int* __restrict__ inv) {
    const int total = (HN * HN) / 4;
    const int stride = gridDim.x * blockDim.x;
    for (int i = blockIdx.x * blockDim.x + threadIdx.x; i < total; i += stride) {
        float4 p = P4[i];
        if (p.x != 0.0f || p.y != 0.0f || p.z != 0.0f || p.w != 0.0f) {
            int base = i << 2;
            int row = base >> 12;        // / 4096
            int col = base & (HN - 1);   // % 4096
            if (p.x != 0.0f) inv[col]     = row;
            if (p.y != 0.0f) inv[col + 1] = row;
            if (p.z != 0.0f) inv[col + 2] = row;
            if (p.w != 0.0f) inv[col + 3] = row;
        }
    }
}

// ---------------------------------------------------------------------------
// 16-point unnormalized Walsh-Hadamard transform in registers (64 add/sub).
// y[p] = sum_q x[q] * (-1)^popcount(p & q)
// ---------------------------------------------------------------------------
__device__ __forceinline__ void fwht16(float* x) {
#pragma unroll
    for (int s = 1; s < 16; s <<= 1) {
#pragma unroll
        for (int i = 0; i < 16; ++i) {
            if ((i & s) == 0) {
                float u = x[i], w = x[i + s];
                x[i] = u + w;
                x[i + s] = u - w;
            }
        }
    }
}

// Padded LDS slot for the FWHT work buffer: breaks power-of-2 strides.
// slot(j) = j + 4*(j>>4) + 8*(j>>8); max slot(4095) = 5235.
#define WORK_SZ 5248
// Padded slot for the original-row buffer (gather source): i + 4*(i>>5);
// keeps each thread's 16-float chunk contiguous & 16B-aligned for b128 writes.
#define ORIG_SZ 4608

// ---------------------------------------------------------------------------
// Kernel B: one block per row. out[r,:] = FWHT(v[r,:])/64 + v[r, inv[:]]
// Round 1: bits 0-3 (contiguous, from global regs)
// Round 2: bits 4-7 (LDS stride-20 after padding -> 2-way, free)
// Round 3: bits 8-11 (LDS stride-328 -> 2-way after padding)
//
// NOTE (rounds 1-2 of this session): fusing extract+fwht into one dispatch was
// tried twice and is structurally a loss on this 8-XCD part. Cross-block inv
// handoff needs either cache-maintenance fences (buffer_inv/wbl2: ~1 ms for
// 8K blocks) or agent-scope uncached loads in the epilogue (33.5M coherence-
// point transactions: +120 µs+). The kernel-launch boundary IS the cheapest
// correct release/acquire; inv is then read through normal cached loads.
// ---------------------------------------------------------------------------
__global__ __launch_bounds__(256, 4)
void fwht_perm_kernel(const float* __restrict__ val,
                      const int* __restrict__ inv,
                      float* __restrict__ out) {
    __shared__ __align__(16) float work[WORK_SZ];
    __shared__ __align__(16) float orig[ORIG_SZ];

    const int t = threadIdx.x;
    const int row = blockIdx.x;
    const float* vr = val + (size_t)row * HN;
    float* outr = out + (size_t)row * HN;

    float x[16];

    // ---- Round 1: thread t owns j = 16t + c, c = 0..15 ----
    const float4* vr4 = (const float4*)vr + (t << 2);
    float4 a0 = vr4[0], a1 = vr4[1], a2 = vr4[2], a3 = vr4[3];

    // Save original row for the permutation gather (padded, b128 writes,
    // balanced banks: bases 20t mod 32 cycle through 8 distinct values).
    float4* o4 = (float4*)(orig + (t << 4) + ((t >> 1) << 2));
    o4[0] = a0; o4[1] = a1; o4[2] = a2; o4[3] = a3;

    x[0] = a0.x; x[1] = a0.y; x[2]  = a0.z; x[3]  = a0.w;
    x[4] = a1.x; x[5] = a1.y; x[6]  = a1.z; x[7]  = a1.w;
    x[8] = a2.x; x[9] = a2.y; x[10] = a2.z; x[11] = a2.w;
    x[12] = a3.x; x[13] = a3.y; x[14] = a3.z; x[15] = a3.w;

    fwht16(x);

    // slot(16t + c) = 20t + 8*(t>>4) + c : contiguous, 16B-aligned base.
    float4* w4 = (float4*)(work + 20 * t + ((t >> 4) << 3));
    w4[0] = make_float4(x[0],  x[1],  x[2],  x[3]);
    w4[1] = make_float4(x[4],  x[5],  x[6],  x[7]);
    w4[2] = make_float4(x[8],  x[9],  x[10], x[11]);
    w4[3] = make_float4(x[12], x[13], x[14], x[15]);
    __syncthreads();

    const int hi = t >> 4;
    const int lo = t & 15;

    // ---- Round 2: thread (a=hi, c=lo) owns j = 256a + 16m + c over m ----
    // slot = 328a + 20m + c
    {
        const int base = 328 * hi + lo;
#pragma unroll
        for (int m = 0; m < 16; ++m) x[m] = work[base + 20 * m];
        fwht16(x);
#pragma unroll
        for (int m = 0; m < 16; ++m) work[base + 20 * m] = x[m];
    }
    __syncthreads();

    // ---- Round 3: thread (b=hi, c=lo) owns j = 256m + 16b + c over m ----
    // slot = 328m + 20b + c
    {
        const int base = 20 * hi + lo;
#pragma unroll
        for (int m = 0; m < 16; ++m) x[m] = work[base + 328 * m];
        fwht16(x);
    }

    // ---- Epilogue: out[j] = fwht[j]/64 + orig[inv[j]] ----
    // j = 256m + t : per-instruction wave accesses are 256B contiguous.
    // Split: preload all 16 indices (independent coalesced loads, L1/L2-hot
    // 16 KB), then gather + store. NT stores: out is never re-read; keep the
    // 128 MB write stream from evicting value+P (192 MB) out of the 256 MB L3.
    const int j0 = (hi << 4) | lo;  // == t
    int src[16];
#pragma unroll
    for (int m = 0; m < 16; ++m) src[m] = inv[(m << 8) + j0];
#pragma unroll
    for (int m = 0; m < 16; ++m) {
        int s = src[m];
        int so = s + ((s >> 5) << 2);           // padded orig slot
        __builtin_nontemporal_store(x[m] * 0.015625f + orig[so],
                                    &outr[(m << 8) + j0]);  // 1/64 = 1/sqrt(4096)
    }
}

extern "C" void kernel_launch(void* const* d_in, const int* in_sizes, int n_in,
                              void* d_out, int out_size, void* d_ws, size_t ws_size,
                              hipStream_t stream) {
    const float* value = (const float*)d_in[0];
    // d_in[1] (weight) is the Sylvester Hadamard matrix / sqrt(N) by
    // construction -- computed analytically via FWHT, never read.
    const float* permutation = (const float*)d_in[2];
    float* out = (float*)d_out;
    int* inv = (int*)d_ws;  // 4096 ints; fully rewritten every call

    extract_inv_kernel<<<2048, 256, 0, stream>>>((const float4*)permutation, inv);
    fwht_perm_kernel<<<HROWS, 256, 0, stream>>>(value, inv, out);
}